// Round 11
// baseline (12455.891 us; speedup 1.0000x reference)
//
#include <hip/hip_runtime.h>
#include <hip/hip_bf16.h>

typedef __bf16 bf16x8 __attribute__((ext_vector_type(8)));
typedef float f32x4 __attribute__((ext_vector_type(4)));
typedef int intx4 __attribute__((ext_vector_type(4)));

#define TT 256
#define BB 64
#define VOC 512
#define EMBD 256
#define NNH 1536
#define KA 1792   // EMBD + NNH
#define KB 3072   // NNH + NNH
#define G4I 6144  // 4*NNH

// frag-state buffer: 48 kc-chunks x 4 m x (hi 512 + lo 512) bf16
#define FRSZ 196608
// emb frag per t: 8 kc x 4 m x 1024 bf16
#define EFSZ 32768

// raw buffer load intrinsic (CK-style asm-name declaration); cachepolicy is immarg.
// cpol=16 sets SC1: agent-scope load -> bypasses per-XCD L2 (not cross-coherent),
// served & RETAINED by the memory-side Infinity Cache (NT=0). B-stream depollution.
__device__ intx4 llvm_amdgcn_raw_buffer_load_i32x4(intx4 srsrc, int voffset,
                                                   int soffset, int cpol)
    __asm("llvm.amdgcn.raw.buffer.load.v4i32");

__device__ __forceinline__ intx4 make_rs(const __bf16* p){
  unsigned long long ba = (unsigned long long)(uintptr_t)p;
  int lo = __builtin_amdgcn_readfirstlane((int)(unsigned)(ba & 0xffffffffull));
  int hi = __builtin_amdgcn_readfirstlane((int)(unsigned)(ba >> 32));
  intx4 rs = { lo, hi, -1, 0x00020000 };   // num_records=0xFFFFFFFF: bounds check off
  return rs;
}

__device__ __forceinline__ float sigm_(float x){
  x = fminf(fmaxf(x, -30.f), 30.f);
  return 1.f / (1.f + __expf(-x));
}
__device__ __forceinline__ float tanh_(float x){
  x = fminf(fmaxf(x, -15.f), 15.f);
  float e = __expf(2.f * x);
  return (e - 1.f) / (e + 1.f);
}

// ---- transpose + hi/lo split: src (R,C) f32 -> dst (C,R) bf16 hi/lo (for ewT/owT)
__global__ __launch_bounds__(256) void tsplit(const float* __restrict__ src, int R, int C,
                                              __bf16* __restrict__ dhi, __bf16* __restrict__ dlo){
  __shared__ float tile[32][33];
  int c0 = blockIdx.x * 32, r0 = blockIdx.y * 32;
  int tx = threadIdx.x & 31, ty = threadIdx.x >> 5;
  #pragma unroll
  for (int i = 0; i < 4; i++){
    int r = ty + i * 8;
    tile[r][tx] = src[(size_t)(r0 + r) * C + (c0 + tx)];
  }
  __syncthreads();
  #pragma unroll
  for (int i = 0; i < 4; i++){
    int cl = ty + i * 8;
    float v = tile[tx][cl];
    __bf16 h = (__bf16)v;
    size_t o = (size_t)(c0 + cl) * R + (r0 + tx);
    dhi[o] = h;
    dlo[o] = (__bf16)(v - (float)h);
  }
}

// ---- elementwise hi/lo split (x input)
__global__ __launch_bounds__(256) void vsplit(const float* __restrict__ src, int n,
                                              __bf16* __restrict__ dhi, __bf16* __restrict__ dlo){
  int i = blockIdx.x * 256 + threadIdx.x;
  if (i < n){
    float v = src[i];
    __bf16 h = (__bf16)v;
    dhi[i] = h;
    dlo[i] = (__bf16)(v - (float)h);
  }
}

// ---- h-state (64,1536) f32 -> frag-order hi/lo
__global__ __launch_bounds__(256) void vsplit_frag(const float* __restrict__ src,
                                                   __bf16* __restrict__ dst){
  int i = blockIdx.x * 256 + threadIdx.x;   // 0..98303
  int b = i / NNH, n = i % NNH;
  float v = src[i];
  __bf16 h = (__bf16)v;
  int kc = n >> 5, lgA = (n >> 3) & 3, j = n & 7;
  size_t idx = (size_t)(kc * 4 + (b >> 4)) * 1024 + (size_t)(lgA * 16 + (b & 15)) * 8 + j;
  dst[idx] = h;
  dst[idx + 512] = (__bf16)(v - (float)h);
}

// ---- weights (K,6144) f32 -> frag stream [b(96)][kc(nkc)][g(4)][hi 512 | lo 512] bf16
__global__ __launch_bounds__(256) void wfrag(const float* __restrict__ w, int nkc,
                                             __bf16* __restrict__ dst){
  int cid = blockIdx.x * 4 + (threadIdx.x >> 6);
  int lane = threadIdx.x & 63;
  int g = cid & 3;
  int bk = cid >> 2;
  int kc = bk % nkc;
  int b = bk / nkc;
  int l15 = lane & 15, lg = lane >> 4;
  int col = g * NNH + b * 16 + l15;
  int k0 = kc * 32 + lg * 8;
  bf16x8 hv, lv;
  #pragma unroll
  for (int j = 0; j < 8; j++){
    float v = w[(size_t)(k0 + j) * G4I + col];
    __bf16 h = (__bf16)v;
    hv[j] = h;
    lv[j] = (__bf16)(v - (float)h);
  }
  __bf16* dh = dst + (size_t)cid * 1024 + lane * 8;
  *(bf16x8*)dh = hv;
  *(bf16x8*)(dh + 512) = lv;
}

// ---- embedding GEMM: x(16384,512) @ emb_w -> emb, written in FRAG order per t
__global__ __launch_bounds__(256) void gemm_emb(const __bf16* __restrict__ Ah, const __bf16* __restrict__ Al,
    const __bf16* __restrict__ BTh, const __bf16* __restrict__ BTl, __bf16* __restrict__ embf){
  int lane = threadIdx.x & 63, wv = threadIdx.x >> 6;
  int l15 = lane & 15, lg = lane >> 4;
  int col = blockIdx.y * 64 + wv * 16 + l15;
  const __bf16* bh_p = BTh + (size_t)col * VOC + lg * 8;
  const __bf16* bl_p = BTl + (size_t)col * VOC + lg * 8;
  size_t abase = (size_t)(blockIdx.x * 64 + l15) * VOC + lg * 8;
  const __bf16* ah_p = Ah + abase;
  const __bf16* al_p = Al + abase;
  f32x4 acc[4];
  #pragma unroll
  for (int m = 0; m < 4; m++){ acc[m][0]=0.f; acc[m][1]=0.f; acc[m][2]=0.f; acc[m][3]=0.f; }
  for (int kc = 0; kc < 16; ++kc){
    bf16x8 bh = *(const bf16x8*)(bh_p + kc * 32);
    bf16x8 bl = *(const bf16x8*)(bl_p + kc * 32);
    bf16x8 ah[4], al[4];
    #pragma unroll
    for (int m = 0; m < 4; m++){
      ah[m] = *(const bf16x8*)(ah_p + (size_t)(m * 16) * VOC + kc * 32);
      al[m] = *(const bf16x8*)(al_p + (size_t)(m * 16) * VOC + kc * 32);
    }
    #pragma unroll
    for (int m = 0; m < 4; m++) acc[m] = __builtin_amdgcn_mfma_f32_16x16x32_bf16(ah[m], bh, acc[m], 0, 0, 0);
    #pragma unroll
    for (int m = 0; m < 4; m++) acc[m] = __builtin_amdgcn_mfma_f32_16x16x32_bf16(al[m], bh, acc[m], 0, 0, 0);
    #pragma unroll
    for (int m = 0; m < 4; m++) acc[m] = __builtin_amdgcn_mfma_f32_16x16x32_bf16(ah[m], bl, acc[m], 0, 0, 0);
  }
  // frag-order epilogue: t = blockIdx.x, k-dim = col
  __bf16* bt = embf + (size_t)blockIdx.x * EFSZ;
  int kc = col >> 5, lgA = (col >> 3) & 3, jA = col & 7;
  #pragma unroll
  for (int m = 0; m < 4; m++){
    #pragma unroll
    for (int v = 0; v < 4; v++){
      int l15A = lg * 4 + v;
      size_t oi = (size_t)(kc * 4 + m) * 1024 + (size_t)(lgA * 16 + l15A) * 8 + jA;
      float x = acc[m][v];
      __bf16 h = (__bf16)x;
      bt[oi] = h;
      bt[oi + 512] = (__bf16)(x - (float)h);
    }
  }
}

// ==== gate-bundled K-split region, A-ring depth 2 (flat/cached), B-ring depth 3
// ==== (buffer loads, SC1 = L2-bypass / L3-retained)
#define AKG(S, KC) { _Pragma("unroll") \
    for (int m = 0; m < 4; m++){ \
      const __bf16* _a = ap + (size_t)(KC) * 4096 + m * 1024 + lane8; \
      Ah##S[m] = *(const bf16x8*)_a; Al##S[m] = *(const bf16x8*)(_a + 512); } }
#define BKG(S, KC) { _Pragma("unroll") \
    for (int g = 0; g < 4; g++){ \
      int _vo = ((KC) * 4096 + g * 1024 + lane8) * 2; \
      Bh##S[g] = __builtin_bit_cast(bf16x8, llvm_amdgcn_raw_buffer_load_i32x4(rs, _vo, 0, 16)); \
      Bl##S[g] = __builtin_bit_cast(bf16x8, llvm_amdgcn_raw_buffer_load_i32x4(rs, _vo + 1024, 0, 16)); \
    } }
#define MM2(SA, SB) { \
    _Pragma("unroll") for (int m = 0; m < 4; m++) _Pragma("unroll") for (int g = 0; g < 4; g++) \
      acc[m * 4 + g] = __builtin_amdgcn_mfma_f32_16x16x32_bf16(Ah##SA[m], Bh##SB[g], acc[m * 4 + g], 0, 0, 0); \
    _Pragma("unroll") for (int m = 0; m < 4; m++) _Pragma("unroll") for (int g = 0; g < 4; g++) \
      acc[m * 4 + g] = __builtin_amdgcn_mfma_f32_16x16x32_bf16(Al##SA[m], Bh##SB[g], acc[m * 4 + g], 0, 0, 0); \
    _Pragma("unroll") for (int m = 0; m < 4; m++) _Pragma("unroll") for (int g = 0; g < 4; g++) \
      acc[m * 4 + g] = __builtin_amdgcn_mfma_f32_16x16x32_bf16(Ah##SA[m], Bl##SB[g], acc[m * 4 + g], 0, 0, 0); }

// body i: consume A-set i&1 / B-set i%3, then reload them for kc i+2 / i+3
#define BODY(I, SA, SB) \
  if ((I) < nkc){ \
    MM2(SA, SB) \
    if ((I) + 2 < nkc) AKG(SA, (I) + 2) \
    if ((I) + 3 < nkc) BKG(SB, (I) + 3) \
  }

// nkc in {6,7,8,12}; fully unrolled 12 slots, wave-uniform guards
__device__ __forceinline__ void regionKG(f32x4 (&acc)[16], const __bf16* __restrict__ ap,
                                         const __bf16* __restrict__ bp, int nkc, int lane8)
{
  intx4 rs = make_rs(bp);
  bf16x8 Ah0[4], Al0[4], Ah1[4], Al1[4];
  bf16x8 Bh0[4], Bl0[4], Bh1[4], Bl1[4], Bh2[4], Bl2[4];
  AKG(0, 0) AKG(1, 1)
  BKG(0, 0) BKG(1, 1) BKG(2, 2)
  BODY(0, 0, 0)
  BODY(1, 1, 1)
  BODY(2, 0, 2)
  BODY(3, 1, 0)
  BODY(4, 0, 1)
  BODY(5, 1, 2)
  BODY(6, 0, 0)
  BODY(7, 1, 1)
  BODY(8, 0, 2)
  BODY(9, 1, 0)
  BODY(10, 0, 1)
  BODY(11, 1, 2)
}

// ---- fused pipelined LSTM step:
//   blocks 0..95   = layer0 step k
//   blocks 96..191 = layer1 step k-1 (h1 kept in a hot 4-slot ring)
//   blocks 192..199 = output projection for t = k-2 (direct logits, NT stores)
__global__ __launch_bounds__(512, 2) void lstm_step(int k,
  const __bf16* __restrict__ w0f, const __bf16* __restrict__ w1f,
  const float* __restrict__ b0, const float* __restrict__ b1,
  const __bf16* __restrict__ embt,
  const __bf16* __restrict__ h0r, __bf16* __restrict__ h0w,
  __bf16* __restrict__ h1f,
  const __bf16* __restrict__ owTh, const __bf16* __restrict__ owTl,
  const float* __restrict__ outb, float* __restrict__ logits,
  float* __restrict__ c0, float* __restrict__ c1)
{
  const int lane = threadIdx.x & 63, wv = threadIdx.x >> 6;
  const int l15 = lane & 15, lg = lane >> 4;
  const int lane8 = lane * 8;

  if (blockIdx.x >= 192){
    // ---- output projection for t = k-2 (4 waves used; no barriers on this path)
    if (k < 2 || wv >= 4) return;
    const int t = k - 2;
    const __bf16* ab = h1f + (size_t)(t & 3) * FRSZ;   // h1(t) ring slot
    const int col = (blockIdx.x - 192) * 64 + wv * 16 + l15;
    const __bf16* bh_p = owTh + (size_t)col * NNH + lg * 8;
    const __bf16* bl_p = owTl + (size_t)col * NNH + lg * 8;
    f32x4 acc[4];
    #pragma unroll
    for (int m = 0; m < 4; m++){ acc[m][0]=0.f; acc[m][1]=0.f; acc[m][2]=0.f; acc[m][3]=0.f; }
    for (int kc = 0; kc < 48; ++kc){
      bf16x8 bh = *(const bf16x8*)(bh_p + kc * 32);
      bf16x8 bl = *(const bf16x8*)(bl_p + kc * 32);
      bf16x8 ah[4], al[4];
      #pragma unroll
      for (int m = 0; m < 4; m++){
        const __bf16* ap2 = ab + (size_t)(kc * 4 + m) * 1024 + lane8;
        ah[m] = *(const bf16x8*)ap2;
        al[m] = *(const bf16x8*)(ap2 + 512);
      }
      #pragma unroll
      for (int m = 0; m < 4; m++) acc[m] = __builtin_amdgcn_mfma_f32_16x16x32_bf16(ah[m], bh, acc[m], 0, 0, 0);
      #pragma unroll
      for (int m = 0; m < 4; m++) acc[m] = __builtin_amdgcn_mfma_f32_16x16x32_bf16(al[m], bh, acc[m], 0, 0, 0);
      #pragma unroll
      for (int m = 0; m < 4; m++) acc[m] = __builtin_amdgcn_mfma_f32_16x16x32_bf16(ah[m], bl, acc[m], 0, 0, 0);
    }
    float bcol = outb[col];
    #pragma unroll
    for (int m = 0; m < 4; m++){
      int row = t * 64 + m * 16 + lg * 4;
      #pragma unroll
      for (int v = 0; v < 4; v++)
        __builtin_nontemporal_store(acc[m][v] + bcol, &logits[(size_t)(row + v) * VOC + col]);
    }
    return;
  }

  const bool isB = blockIdx.x >= 96;
  if (!isB && k >= TT) return;
  if (isB && (k == 0 || k > TT)) return;
  const int blk = isB ? (blockIdx.x - 96) : blockIdx.x;
  const int n0 = blk * 16;
  const __bf16* h1r = h1f + (size_t)((k + 2) & 3) * FRSZ;   // h1(k-2)
  __bf16* h1w = h1f + (size_t)((k + 3) & 3) * FRSZ;         // h1(k-1)

  f32x4 acc[16];
  #pragma unroll
  for (int i = 0; i < 16; i++){ acc[i][0]=0.f; acc[i][1]=0.f; acc[i][2]=0.f; acc[i][3]=0.f; }

  if (isB){
    // 96 kc; wave wv: kc [wv*12, wv*12+12); waves 0-3 read h0(k-1), 4-7 read h1(k-2)
    const __bf16* ap = (wv < 4) ? (h0r + (size_t)(wv * 12) * 4096)
                                : (h1r + (size_t)((wv - 4) * 12) * 4096);
    const __bf16* bp = w1f + ((size_t)blk * 96 + wv * 12) * 4096;
    regionKG(acc, ap, bp, 12, lane8);
  } else {
    // 56 kc = [emb 8 | h0 48]; quotas: wv0=8(emb), wv1-6=7, wv7=6
    int gstart = (wv == 0) ? 0 : (8 + (wv - 1) * 7);
    int nkc = (wv == 0) ? 8 : ((wv == 7) ? 6 : 7);
    const __bf16* ap = (wv == 0) ? embt : (h0r + (size_t)(gstart - 8) * 4096);
    const __bf16* bp = w0f + ((size_t)blk * 56 + gstart) * 4096;
    regionKG(acc, ap, bp, nkc, lane8);
  }

  // two-stage K-partial reduction: 8 partials -> 4 in LDS -> epilogue sums 4
  __shared__ float lin[4][64][68];   // [wavepair][col(g*16+l15)][row(batch), pad 68], ~68 KB
  if (wv >= 4){
    #pragma unroll
    for (int m = 0; m < 4; m++)
      #pragma unroll
      for (int g = 0; g < 4; g++)
        *(f32x4*)&lin[wv - 4][g * 16 + l15][m * 16 + lg * 4] = acc[m * 4 + g];
  }
  __syncthreads();
  if (wv < 4){
    #pragma unroll
    for (int m = 0; m < 4; m++)
      #pragma unroll
      for (int g = 0; g < 4; g++){
        f32x4 part = *(const f32x4*)&lin[wv][g * 16 + l15][m * 16 + lg * 4];
        acc[m * 4 + g][0] += part[0]; acc[m * 4 + g][1] += part[1];
        acc[m * 4 + g][2] += part[2]; acc[m * 4 + g][3] += part[3];
        *(f32x4*)&lin[wv][g * 16 + l15][m * 16 + lg * 4] = acc[m * 4 + g];
      }
  }
  __syncthreads();

  const float* bias = isB ? b1 : b0;
  float* cst = isB ? c1 : c0;
  __bf16* of = isB ? h1w : h0w;
  const int j = threadIdx.x & 15, rr = threadIdx.x >> 4;   // j: n_rel, rr: 0..31
  #pragma unroll
  for (int half = 0; half < 2; half++){
    int r = rr + half * 32;   // batch row
    float s0 = 0.f, s1 = 0.f, s2 = 0.f, s3 = 0.f;
    #pragma unroll
    for (int w = 0; w < 4; w++){
      s0 += lin[w][j][r];
      s1 += lin[w][16 + j][r];
      s2 += lin[w][32 + j][r];
      s3 += lin[w][48 + j][r];
    }
    int n = n0 + j;
    float fv = sigm_(s0 + bias[n]);
    float iv = sigm_(s1 + bias[NNH + n]);
    float ov = sigm_(s2 + bias[2 * NNH + n]);
    float gv = tanh_(s3 + bias[3 * NNH + n]);
    int ci = r * NNH + n;
    float cn = fv * cst[ci] + iv * gv;
    cst[ci] = cn;
    float hn = ov * tanh_(cn);
    __bf16 hb = (__bf16)hn;
    int kcp = n >> 5, lgA = (n >> 3) & 3, j8 = n & 7, mb = r >> 4, l15b = r & 15;
    size_t oi = (size_t)(kcp * 4 + mb) * 1024 + (size_t)(lgA * 16 + l15b) * 8 + j8;
    of[oi] = hb;
    of[oi + 512] = (__bf16)(hn - (float)hb);
  }
}

extern "C" void kernel_launch(void* const* d_in, const int* in_sizes, int n_in,
                              void* d_out, int out_size, void* d_ws, size_t ws_size,
                              hipStream_t stream)
{
  (void)in_sizes; (void)n_in; (void)out_size;
  const float* x_in = (const float*)d_in[0];
  const float* emw  = (const float*)d_in[1];
  const float* w0   = (const float*)d_in[2];
  const float* b0   = (const float*)d_in[3];
  const float* w1   = (const float*)d_in[4];
  const float* b1   = (const float*)d_in[5];
  const float* outw = (const float*)d_in[6];
  const float* outb = (const float*)d_in[7];
  const float* h0i  = (const float*)d_in[8];
  const float* c0i  = (const float*)d_in[9];
  const float* h1i  = (const float*)d_in[10];
  const float* c1i  = (const float*)d_in[11];
  float* logits = (float*)d_out;

  char* p = (char*)d_ws;
  auto ab = [&](size_t bytes)->char*{ char* r = p; p += (bytes + 255) & ~(size_t)255; return r; };
  __bf16* w0f  = (__bf16*)ab((size_t)96 * 56 * 4 * 2048);   // 44.0 MB frag stream
  __bf16* w1f  = (__bf16*)ab((size_t)96 * 96 * 4 * 2048);   // 75.5 MB
  __bf16* ewTh = (__bf16*)ab((size_t)EMBD * VOC * 2);
  __bf16* ewTl = (__bf16*)ab((size_t)EMBD * VOC * 2);
  __bf16* owTh = (__bf16*)ab((size_t)VOC * NNH * 2);
  __bf16* owTl = (__bf16*)ab((size_t)VOC * NNH * 2);
  __bf16* xh   = (__bf16*)ab((size_t)TT * BB * VOC * 2);
  __bf16* xl   = (__bf16*)ab((size_t)TT * BB * VOC * 2);
  __bf16* embf = (__bf16*)ab((size_t)TT * EFSZ * 2);        // 16.8 MB frag
  __bf16* h0f  = (__bf16*)ab((size_t)2 * FRSZ * 2);         // h0 ping-pong frag (hot)
  __bf16* h1f  = (__bf16*)ab((size_t)4 * FRSZ * 2);         // h1 4-slot ring (hot)
  float* c0 = (float*)ab((size_t)BB * NNH * 4);
  float* c1 = (float*)ab((size_t)BB * NNH * 4);
  if ((size_t)(p - (char*)d_ws) > ws_size) return;  // ws too small: fail visibly

  const int H = BB * NNH;

  // one-time-per-call prep
  wfrag<<<96 * 56 * 4 / 4, 256, 0, stream>>>(w0, 56, w0f);
  wfrag<<<96 * 96 * 4 / 4, 256, 0, stream>>>(w1, 96, w1f);
  tsplit<<<dim3(EMBD / 32, VOC / 32), 256, 0, stream>>>(emw, VOC, EMBD, ewTh, ewTl);
  tsplit<<<dim3(VOC / 32, NNH / 32), 256, 0, stream>>>(outw, NNH, VOC, owTh, owTl);
  {
    int nin = TT * BB * VOC;
    vsplit<<<nin / 256, 256, 0, stream>>>(x_in, nin, xh, xl);
  }
  vsplit_frag<<<H / 256, 256, 0, stream>>>(h0i, h0f + FRSZ);            // h0 parity 1 (read at k=0)
  vsplit_frag<<<H / 256, 256, 0, stream>>>(h1i, h1f + (size_t)3 * FRSZ); // h1(-1) -> ring slot 3
  hipMemcpyAsync(c0, c0i, (size_t)H * 4, hipMemcpyDeviceToDevice, stream);
  hipMemcpyAsync(c1, c1i, (size_t)H * 4, hipMemcpyDeviceToDevice, stream);

  // embedding -> frag-order emb buffer
  gemm_emb<<<dim3(TT * BB / 64, EMBD / 64), 256, 0, stream>>>(xh, xl, ewTh, ewTl, embf);

  // pipelined recurrence: kernel k = layer0(k) + layer1(k-1) + out-projection(k-2)
  for (int k = 0; k <= TT + 1; ++k){
    int tA = (k < TT) ? k : 0;
    lstm_step<<<200, 512, 0, stream>>>(k, w0f, w1f, b0, b1,
        embf + (size_t)tA * EFSZ,
        h0f + (size_t)((k + 1) & 1) * FRSZ, h0f + (size_t)(k & 1) * FRSZ,
        h1f, owTh, owTl, outb, logits, c0, c1);
  }
}

// Round 12
// 5978.300 us; speedup vs baseline: 2.0835x; 2.0835x over previous
//
#include <hip/hip_runtime.h>
#include <hip/hip_bf16.h>

typedef __bf16 bf16x8 __attribute__((ext_vector_type(8)));
typedef float f32x4 __attribute__((ext_vector_type(4)));

#define TT 256
#define BB 64
#define VOC 512
#define EMBD 256
#define NNH 1536
#define KA 1792   // EMBD + NNH
#define KB 3072   // NNH + NNH
#define G4I 6144  // 4*NNH

// frag-state buffer: 48 kc-chunks x 4 m x (hi 512 + lo 512) bf16
#define FRSZ 196608
// emb frag per t: 8 kc x 4 m x 1024 bf16
#define EFSZ 32768

__device__ __forceinline__ float sigm_(float x){
  x = fminf(fmaxf(x, -30.f), 30.f);
  return 1.f / (1.f + __expf(-x));
}
__device__ __forceinline__ float tanh_(float x){
  x = fminf(fmaxf(x, -15.f), 15.f);
  float e = __expf(2.f * x);
  return (e - 1.f) / (e + 1.f);
}

// ---- transpose + hi/lo split: src (R,C) f32 -> dst (C,R) bf16 hi/lo (for ewT/owT)
__global__ __launch_bounds__(256) void tsplit(const float* __restrict__ src, int R, int C,
                                              __bf16* __restrict__ dhi, __bf16* __restrict__ dlo){
  __shared__ float tile[32][33];
  int c0 = blockIdx.x * 32, r0 = blockIdx.y * 32;
  int tx = threadIdx.x & 31, ty = threadIdx.x >> 5;
  #pragma unroll
  for (int i = 0; i < 4; i++){
    int r = ty + i * 8;
    tile[r][tx] = src[(size_t)(r0 + r) * C + (c0 + tx)];
  }
  __syncthreads();
  #pragma unroll
  for (int i = 0; i < 4; i++){
    int cl = ty + i * 8;
    float v = tile[tx][cl];
    __bf16 h = (__bf16)v;
    size_t o = (size_t)(c0 + cl) * R + (r0 + tx);
    dhi[o] = h;
    dlo[o] = (__bf16)(v - (float)h);
  }
}

// ---- elementwise hi/lo split (x input)
__global__ __launch_bounds__(256) void vsplit(const float* __restrict__ src, int n,
                                              __bf16* __restrict__ dhi, __bf16* __restrict__ dlo){
  int i = blockIdx.x * 256 + threadIdx.x;
  if (i < n){
    float v = src[i];
    __bf16 h = (__bf16)v;
    dhi[i] = h;
    dlo[i] = (__bf16)(v - (float)h);
  }
}

// ---- h-state (64,1536) f32 -> frag-order hi/lo
__global__ __launch_bounds__(256) void vsplit_frag(const float* __restrict__ src,
                                                   __bf16* __restrict__ dst){
  int i = blockIdx.x * 256 + threadIdx.x;   // 0..98303
  int b = i / NNH, n = i % NNH;
  float v = src[i];
  __bf16 h = (__bf16)v;
  int kc = n >> 5, lgA = (n >> 3) & 3, j = n & 7;
  size_t idx = (size_t)(kc * 4 + (b >> 4)) * 1024 + (size_t)(lgA * 16 + (b & 15)) * 8 + j;
  dst[idx] = h;
  dst[idx + 512] = (__bf16)(v - (float)h);
}

// ---- weights (K,6144) f32 -> HI-ONLY frag stream [b(96)][kc(nkc)][g(4)][512 bf16]
__global__ __launch_bounds__(256) void wfrag(const float* __restrict__ w, int nkc,
                                             __bf16* __restrict__ dst){
  int cid = blockIdx.x * 4 + (threadIdx.x >> 6);
  int lane = threadIdx.x & 63;
  int g = cid & 3;
  int bk = cid >> 2;
  int kc = bk % nkc;
  int b = bk / nkc;
  int l15 = lane & 15, lg = lane >> 4;
  int col = g * NNH + b * 16 + l15;
  int k0 = kc * 32 + lg * 8;
  bf16x8 hv;
  #pragma unroll
  for (int j = 0; j < 8; j++)
    hv[j] = (__bf16)w[(size_t)(k0 + j) * G4I + col];
  *(bf16x8*)(dst + (size_t)cid * 512 + lane * 8) = hv;
}

// ---- embedding GEMM (3-pass, exact): x(16384,512) @ emb_w -> emb frag order per t
__global__ __launch_bounds__(256) void gemm_emb(const __bf16* __restrict__ Ah, const __bf16* __restrict__ Al,
    const __bf16* __restrict__ BTh, const __bf16* __restrict__ BTl, __bf16* __restrict__ embf){
  int lane = threadIdx.x & 63, wv = threadIdx.x >> 6;
  int l15 = lane & 15, lg = lane >> 4;
  int col = blockIdx.y * 64 + wv * 16 + l15;
  const __bf16* bh_p = BTh + (size_t)col * VOC + lg * 8;
  const __bf16* bl_p = BTl + (size_t)col * VOC + lg * 8;
  size_t abase = (size_t)(blockIdx.x * 64 + l15) * VOC + lg * 8;
  const __bf16* ah_p = Ah + abase;
  const __bf16* al_p = Al + abase;
  f32x4 acc[4];
  #pragma unroll
  for (int m = 0; m < 4; m++){ acc[m][0]=0.f; acc[m][1]=0.f; acc[m][2]=0.f; acc[m][3]=0.f; }
  for (int kc = 0; kc < 16; ++kc){
    bf16x8 bh = *(const bf16x8*)(bh_p + kc * 32);
    bf16x8 bl = *(const bf16x8*)(bl_p + kc * 32);
    bf16x8 ah[4], al[4];
    #pragma unroll
    for (int m = 0; m < 4; m++){
      ah[m] = *(const bf16x8*)(ah_p + (size_t)(m * 16) * VOC + kc * 32);
      al[m] = *(const bf16x8*)(al_p + (size_t)(m * 16) * VOC + kc * 32);
    }
    #pragma unroll
    for (int m = 0; m < 4; m++) acc[m] = __builtin_amdgcn_mfma_f32_16x16x32_bf16(ah[m], bh, acc[m], 0, 0, 0);
    #pragma unroll
    for (int m = 0; m < 4; m++) acc[m] = __builtin_amdgcn_mfma_f32_16x16x32_bf16(al[m], bh, acc[m], 0, 0, 0);
    #pragma unroll
    for (int m = 0; m < 4; m++) acc[m] = __builtin_amdgcn_mfma_f32_16x16x32_bf16(ah[m], bl, acc[m], 0, 0, 0);
  }
  // frag-order epilogue: t = blockIdx.x, k-dim = col
  __bf16* bt = embf + (size_t)blockIdx.x * EFSZ;
  int kc = col >> 5, lgA = (col >> 3) & 3, jA = col & 7;
  #pragma unroll
  for (int m = 0; m < 4; m++){
    #pragma unroll
    for (int v = 0; v < 4; v++){
      int l15A = lg * 4 + v;
      size_t oi = (size_t)(kc * 4 + m) * 1024 + (size_t)(lgA * 16 + l15A) * 8 + jA;
      float x = acc[m][v];
      __bf16 h = (__bf16)x;
      bt[oi] = h;
      bt[oi + 512] = (__bf16)(x - (float)h);
    }
  }
}

// ---- output GEMM (3-pass, exact): rn frag history @ out_w + bias -> logits f32
__global__ __launch_bounds__(256) void gemm_out(const __bf16* __restrict__ rnf,
    const __bf16* __restrict__ BTh, const __bf16* __restrict__ BTl,
    const float* __restrict__ bias, float* __restrict__ out){
  int lane = threadIdx.x & 63, wv = threadIdx.x >> 6;
  int l15 = lane & 15, lg = lane >> 4;
  int t = blockIdx.x;
  const __bf16* ab = rnf + (size_t)(t + 1) * FRSZ;
  int col = blockIdx.y * 64 + wv * 16 + l15;
  const __bf16* bh_p = BTh + (size_t)col * NNH + lg * 8;
  const __bf16* bl_p = BTl + (size_t)col * NNH + lg * 8;
  int lane8 = lane * 8;
  f32x4 acc[4];
  #pragma unroll
  for (int m = 0; m < 4; m++){ acc[m][0]=0.f; acc[m][1]=0.f; acc[m][2]=0.f; acc[m][3]=0.f; }
  for (int kc = 0; kc < 48; ++kc){
    bf16x8 bh = *(const bf16x8*)(bh_p + kc * 32);
    bf16x8 bl = *(const bf16x8*)(bl_p + kc * 32);
    bf16x8 ah[4], al[4];
    #pragma unroll
    for (int m = 0; m < 4; m++){
      const __bf16* ap = ab + (size_t)(kc * 4 + m) * 1024 + lane8;
      ah[m] = *(const bf16x8*)ap;
      al[m] = *(const bf16x8*)(ap + 512);
    }
    #pragma unroll
    for (int m = 0; m < 4; m++) acc[m] = __builtin_amdgcn_mfma_f32_16x16x32_bf16(ah[m], bh, acc[m], 0, 0, 0);
    #pragma unroll
    for (int m = 0; m < 4; m++) acc[m] = __builtin_amdgcn_mfma_f32_16x16x32_bf16(al[m], bh, acc[m], 0, 0, 0);
    #pragma unroll
    for (int m = 0; m < 4; m++) acc[m] = __builtin_amdgcn_mfma_f32_16x16x32_bf16(ah[m], bl, acc[m], 0, 0, 0);
  }
  #pragma unroll
  for (int m = 0; m < 4; m++){
    int row = t * 64 + m * 16 + lg * 4;
    #pragma unroll
    for (int v = 0; v < 4; v++)
      out[(size_t)(row + v) * VOC + col] = acc[m][v] + bias[col];
  }
}

// ==== 2-pass gate-bundled K-split region: A hi/lo (exact), B hi-only ====
// per kc: load 8 A-frags + 4 B-frags, 32 MFMAs. A-ring depth 2, B-ring depth 3.
#define AKG(S, KC) { _Pragma("unroll") \
    for (int m = 0; m < 4; m++){ \
      const __bf16* _a = ap + (size_t)(KC) * 4096 + m * 1024 + lane8; \
      Ah##S[m] = *(const bf16x8*)_a; Al##S[m] = *(const bf16x8*)(_a + 512); } }
#define BKG(S, KC) { _Pragma("unroll") \
    for (int g = 0; g < 4; g++){ \
      Bh##S[g] = *(const bf16x8*)(bp + (size_t)(KC) * 2048 + g * 512 + lane8); } }
#define MM2(SA, SB) { \
    _Pragma("unroll") for (int m = 0; m < 4; m++) _Pragma("unroll") for (int g = 0; g < 4; g++) \
      acc[m * 4 + g] = __builtin_amdgcn_mfma_f32_16x16x32_bf16(Ah##SA[m], Bh##SB[g], acc[m * 4 + g], 0, 0, 0); \
    _Pragma("unroll") for (int m = 0; m < 4; m++) _Pragma("unroll") for (int g = 0; g < 4; g++) \
      acc[m * 4 + g] = __builtin_amdgcn_mfma_f32_16x16x32_bf16(Al##SA[m], Bh##SB[g], acc[m * 4 + g], 0, 0, 0); }

// body i: consume A-set i&1 / B-set i%3, then reload them for kc i+2 / i+3
#define BODY(I, SA, SB) \
  if ((I) < nkc){ \
    MM2(SA, SB) \
    if ((I) + 2 < nkc) AKG(SA, (I) + 2) \
    if ((I) + 3 < nkc) BKG(SB, (I) + 3) \
  }

// nkc in {6,7,8,12}; fully unrolled 12 slots, wave-uniform guards
__device__ __forceinline__ void regionKG(f32x4 (&acc)[16], const __bf16* __restrict__ ap,
                                         const __bf16* __restrict__ bp, int nkc, int lane8)
{
  bf16x8 Ah0[4], Al0[4], Ah1[4], Al1[4];
  bf16x8 Bh0[4], Bh1[4], Bh2[4];
  AKG(0, 0) AKG(1, 1)
  BKG(0, 0) BKG(1, 1) BKG(2, 2)
  BODY(0, 0, 0)
  BODY(1, 1, 1)
  BODY(2, 0, 2)
  BODY(3, 1, 0)
  BODY(4, 0, 1)
  BODY(5, 1, 2)
  BODY(6, 0, 0)
  BODY(7, 1, 1)
  BODY(8, 0, 2)
  BODY(9, 1, 0)
  BODY(10, 0, 1)
  BODY(11, 1, 2)
}

// ---- fused pipelined LSTM step: blocks 0..95 = layer0 step k; 96..191 = layer1 step k-1
// 8 waves: each wave computes full 64-col tile (16 n x 4 gates) over 1/8 of K.
// Two-stage pairwise K-reduction; h1 hot ping-pong + NT history copy for gemm_out.
__global__ __launch_bounds__(512, 2) void lstm_step(int k,
  const __bf16* __restrict__ w0f, const __bf16* __restrict__ w1f,
  const float* __restrict__ b0, const float* __restrict__ b1,
  const __bf16* __restrict__ embt,
  const __bf16* __restrict__ h0r, __bf16* __restrict__ h0w,
  const __bf16* __restrict__ h1r, __bf16* __restrict__ h1w,
  __bf16* __restrict__ rnh,
  float* __restrict__ c0, float* __restrict__ c1)
{
  const bool isB = blockIdx.x >= 96;
  if (!isB && k == TT) return;
  if (isB && k == 0) return;
  const int blk = isB ? (blockIdx.x - 96) : blockIdx.x;
  const int n0 = blk * 16;
  const int lane = threadIdx.x & 63, wv = threadIdx.x >> 6;
  const int l15 = lane & 15, lg = lane >> 4;
  const int lane8 = lane * 8;

  f32x4 acc[16];
  #pragma unroll
  for (int i = 0; i < 16; i++){ acc[i][0]=0.f; acc[i][1]=0.f; acc[i][2]=0.f; acc[i][3]=0.f; }

  if (isB){
    // 96 kc; wave wv: kc [wv*12, wv*12+12); waves 0-3 read h0(t), 4-7 read h1(t-2)
    const __bf16* ap = (wv < 4) ? (h0r + (size_t)(wv * 12) * 4096)
                                : (h1r + (size_t)((wv - 4) * 12) * 4096);
    const __bf16* bp = w1f + ((size_t)blk * 96 + wv * 12) * 2048;
    regionKG(acc, ap, bp, 12, lane8);
  } else {
    // 56 kc = [emb 8 | h0 48]; quotas: wv0=8(emb), wv1-6=7, wv7=6
    int gstart = (wv == 0) ? 0 : (8 + (wv - 1) * 7);
    int nkc = (wv == 0) ? 8 : ((wv == 7) ? 6 : 7);
    const __bf16* ap = (wv == 0) ? embt : (h0r + (size_t)(gstart - 8) * 4096);
    const __bf16* bp = w0f + ((size_t)blk * 56 + gstart) * 2048;
    regionKG(acc, ap, bp, nkc, lane8);
  }

  // two-stage K-partial reduction: 8 partials -> 4 in LDS -> epilogue sums 4
  __shared__ float lin[4][64][68];   // [wavepair][col(g*16+l15)][row(batch), pad 68], ~68 KB
  if (wv >= 4){
    #pragma unroll
    for (int m = 0; m < 4; m++)
      #pragma unroll
      for (int g = 0; g < 4; g++)
        *(f32x4*)&lin[wv - 4][g * 16 + l15][m * 16 + lg * 4] = acc[m * 4 + g];
  }
  __syncthreads();
  if (wv < 4){
    #pragma unroll
    for (int m = 0; m < 4; m++)
      #pragma unroll
      for (int g = 0; g < 4; g++){
        f32x4 part = *(const f32x4*)&lin[wv][g * 16 + l15][m * 16 + lg * 4];
        acc[m * 4 + g][0] += part[0]; acc[m * 4 + g][1] += part[1];
        acc[m * 4 + g][2] += part[2]; acc[m * 4 + g][3] += part[3];
        *(f32x4*)&lin[wv][g * 16 + l15][m * 16 + lg * 4] = acc[m * 4 + g];
      }
  }
  __syncthreads();

  const float* bias = isB ? b1 : b0;
  float* cst = isB ? c1 : c0;
  __bf16* of = isB ? h1w : h0w;
  const int j = threadIdx.x & 15, rr = threadIdx.x >> 4;   // j: n_rel, rr: 0..31
  #pragma unroll
  for (int half = 0; half < 2; half++){
    int r = rr + half * 32;   // batch row
    float s0 = 0.f, s1 = 0.f, s2 = 0.f, s3 = 0.f;
    #pragma unroll
    for (int w = 0; w < 4; w++){
      s0 += lin[w][j][r];
      s1 += lin[w][16 + j][r];
      s2 += lin[w][32 + j][r];
      s3 += lin[w][48 + j][r];
    }
    int n = n0 + j;
    float fv = sigm_(s0 + bias[n]);
    float iv = sigm_(s1 + bias[NNH + n]);
    float ov = sigm_(s2 + bias[2 * NNH + n]);
    float gv = tanh_(s3 + bias[3 * NNH + n]);
    int ci = r * NNH + n;
    float cn = fv * cst[ci] + iv * gv;
    cst[ci] = cn;
    float hn = ov * tanh_(cn);
    __bf16 hb = (__bf16)hn;
    __bf16 lb = (__bf16)(hn - (float)hb);
    int kcp = n >> 5, lgA = (n >> 3) & 3, j8 = n & 7, mb = r >> 4, l15b = r & 15;
    size_t oi = (size_t)(kcp * 4 + mb) * 1024 + (size_t)(lgA * 16 + l15b) * 8 + j8;
    of[oi] = hb;            // hot ping-pong slot (cached, read next step)
    of[oi + 512] = lb;
    if (isB){
      // cold history copy for gemm_out: stream to HBM, keep out of L3
      __builtin_nontemporal_store(hb, &rnh[oi]);
      __builtin_nontemporal_store(lb, &rnh[oi + 512]);
    }
  }
}

extern "C" void kernel_launch(void* const* d_in, const int* in_sizes, int n_in,
                              void* d_out, int out_size, void* d_ws, size_t ws_size,
                              hipStream_t stream)
{
  (void)in_sizes; (void)n_in; (void)out_size;
  const float* x_in = (const float*)d_in[0];
  const float* emw  = (const float*)d_in[1];
  const float* w0   = (const float*)d_in[2];
  const float* b0   = (const float*)d_in[3];
  const float* w1   = (const float*)d_in[4];
  const float* b1   = (const float*)d_in[5];
  const float* outw = (const float*)d_in[6];
  const float* outb = (const float*)d_in[7];
  const float* h0i  = (const float*)d_in[8];
  const float* c0i  = (const float*)d_in[9];
  const float* h1i  = (const float*)d_in[10];
  const float* c1i  = (const float*)d_in[11];
  float* logits = (float*)d_out;

  char* p = (char*)d_ws;
  auto ab = [&](size_t bytes)->char*{ char* r = p; p += (bytes + 255) & ~(size_t)255; return r; };
  __bf16* w0f  = (__bf16*)ab((size_t)96 * 56 * 4 * 1024);   // 22.0 MB hi-only stream
  __bf16* w1f  = (__bf16*)ab((size_t)96 * 96 * 4 * 1024);   // 37.7 MB
  __bf16* ewTh = (__bf16*)ab((size_t)EMBD * VOC * 2);
  __bf16* ewTl = (__bf16*)ab((size_t)EMBD * VOC * 2);
  __bf16* owTh = (__bf16*)ab((size_t)VOC * NNH * 2);
  __bf16* owTl = (__bf16*)ab((size_t)VOC * NNH * 2);
  __bf16* xh   = (__bf16*)ab((size_t)TT * BB * VOC * 2);
  __bf16* xl   = (__bf16*)ab((size_t)TT * BB * VOC * 2);
  __bf16* embf = (__bf16*)ab((size_t)TT * EFSZ * 2);        // 16.8 MB frag
  __bf16* rnf  = (__bf16*)ab((size_t)(TT + 1) * FRSZ * 2);  // 101 MB history (NT-streamed)
  __bf16* h0f  = (__bf16*)ab((size_t)2 * FRSZ * 2);         // h0 ping-pong frag (hot)
  __bf16* h1f  = (__bf16*)ab((size_t)2 * FRSZ * 2);         // h1 ping-pong frag (hot)
  float* c0 = (float*)ab((size_t)BB * NNH * 4);
  float* c1 = (float*)ab((size_t)BB * NNH * 4);
  if ((size_t)(p - (char*)d_ws) > ws_size) return;  // ws too small: fail visibly

  const int H = BB * NNH;

  // one-time-per-call prep
  wfrag<<<96 * 56 * 4 / 4, 256, 0, stream>>>(w0, 56, w0f);
  wfrag<<<96 * 96 * 4 / 4, 256, 0, stream>>>(w1, 96, w1f);
  tsplit<<<dim3(EMBD / 32, VOC / 32), 256, 0, stream>>>(emw, VOC, EMBD, ewTh, ewTl);
  tsplit<<<dim3(VOC / 32, NNH / 32), 256, 0, stream>>>(outw, NNH, VOC, owTh, owTl);
  {
    int nin = TT * BB * VOC;
    vsplit<<<nin / 256, 256, 0, stream>>>(x_in, nin, xh, xl);
  }
  vsplit_frag<<<H / 256, 256, 0, stream>>>(h0i, h0f + FRSZ);  // h0 parity buf 1 (read at k=0)
  vsplit_frag<<<H / 256, 256, 0, stream>>>(h1i, h1f);         // h1 parity buf 0 (read at k=1)
  hipMemcpyAsync(c0, c0i, (size_t)H * 4, hipMemcpyDeviceToDevice, stream);
  hipMemcpyAsync(c1, c1i, (size_t)H * 4, hipMemcpyDeviceToDevice, stream);

  // embedding -> frag-order emb buffer
  gemm_emb<<<dim3(TT * BB / 64, EMBD / 64), 256, 0, stream>>>(xh, xl, ewTh, ewTl, embf);

  // pipelined recurrence: kernel k = layer0 step k + layer1 step k-1
  for (int k = 0; k <= TT; ++k){
    int tA = (k < TT) ? k : 0;
    lstm_step<<<192, 512, 0, stream>>>(k, w0f, w1f, b0, b1,
        embf + (size_t)tA * EFSZ,
        h0f + (size_t)((k + 1) & 1) * FRSZ, h0f + (size_t)(k & 1) * FRSZ,
        h1f + (size_t)((k + 1) & 1) * FRSZ, h1f + (size_t)(k & 1) * FRSZ,
        rnf + (size_t)k * FRSZ,
        c0, c1);
  }

  // logits = rn frag history @ out_w + out_b
  gemm_out<<<dim3(TT, VOC / 64), 256, 0, stream>>>(rnf, owTh, owTl, outb, logits);
}

// Round 13
// 4367.326 us; speedup vs baseline: 2.8521x; 1.3689x over previous
//
#include <hip/hip_runtime.h>
#include <hip/hip_bf16.h>

typedef __bf16 bf16x8 __attribute__((ext_vector_type(8)));
typedef float f32x4 __attribute__((ext_vector_type(4)));

#define TT 256
#define BB 64
#define VOC 512
#define EMBD 256
#define NNH 1536
#define KA 1792   // EMBD + NNH
#define KB 3072   // NNH + NNH
#define G4I 6144  // 4*NNH

// hi/lo frag buffer (rnf history): 48 kc x 4 m x (hi 512 | lo 512)
#define FRSZ 196608
// hi-only frag state (h0/h1/emb): 48 kc x 4 m x 512
#define FRSZH 98304
// emb hi-only frag per t: 8 kc x 4 m x 512
#define EFSZH 16384

__device__ __forceinline__ float sigm_(float x){
  x = fminf(fmaxf(x, -30.f), 30.f);
  return 1.f / (1.f + __expf(-x));
}
__device__ __forceinline__ float tanh_(float x){
  x = fminf(fmaxf(x, -15.f), 15.f);
  float e = __expf(2.f * x);
  return (e - 1.f) / (e + 1.f);
}

// ---- transpose + hi/lo split: src (R,C) f32 -> dst (C,R) bf16 hi/lo (for ewT/owT)
__global__ __launch_bounds__(256) void tsplit(const float* __restrict__ src, int R, int C,
                                              __bf16* __restrict__ dhi, __bf16* __restrict__ dlo){
  __shared__ float tile[32][33];
  int c0 = blockIdx.x * 32, r0 = blockIdx.y * 32;
  int tx = threadIdx.x & 31, ty = threadIdx.x >> 5;
  #pragma unroll
  for (int i = 0; i < 4; i++){
    int r = ty + i * 8;
    tile[r][tx] = src[(size_t)(r0 + r) * C + (c0 + tx)];
  }
  __syncthreads();
  #pragma unroll
  for (int i = 0; i < 4; i++){
    int cl = ty + i * 8;
    float v = tile[tx][cl];
    __bf16 h = (__bf16)v;
    size_t o = (size_t)(c0 + cl) * R + (r0 + tx);
    dhi[o] = h;
    dlo[o] = (__bf16)(v - (float)h);
  }
}

// ---- elementwise hi/lo split (x input)
__global__ __launch_bounds__(256) void vsplit(const float* __restrict__ src, int n,
                                              __bf16* __restrict__ dhi, __bf16* __restrict__ dlo){
  int i = blockIdx.x * 256 + threadIdx.x;
  if (i < n){
    float v = src[i];
    __bf16 h = (__bf16)v;
    dhi[i] = h;
    dlo[i] = (__bf16)(v - (float)h);
  }
}

// ---- h-state (64,1536) f32 -> HI-ONLY frag order
__global__ __launch_bounds__(256) void vsplit_fragH(const float* __restrict__ src,
                                                    __bf16* __restrict__ dst){
  int i = blockIdx.x * 256 + threadIdx.x;   // 0..98303
  int b = i / NNH, n = i % NNH;
  int kc = n >> 5, lgA = (n >> 3) & 3, j = n & 7;
  size_t idx = (size_t)(kc * 4 + (b >> 4)) * 512 + (size_t)(lgA * 16 + (b & 15)) * 8 + j;
  dst[idx] = (__bf16)src[i];
}

// ---- weights (K,6144) f32 -> HI-ONLY frag stream [b(96)][kc(nkc)][g(4)][512 bf16]
__global__ __launch_bounds__(256) void wfrag(const float* __restrict__ w, int nkc,
                                             __bf16* __restrict__ dst){
  int cid = blockIdx.x * 4 + (threadIdx.x >> 6);
  int lane = threadIdx.x & 63;
  int g = cid & 3;
  int bk = cid >> 2;
  int kc = bk % nkc;
  int b = bk / nkc;
  int l15 = lane & 15, lg = lane >> 4;
  int col = g * NNH + b * 16 + l15;
  int k0 = kc * 32 + lg * 8;
  bf16x8 hv;
  #pragma unroll
  for (int j = 0; j < 8; j++)
    hv[j] = (__bf16)w[(size_t)(k0 + j) * G4I + col];
  *(bf16x8*)(dst + (size_t)cid * 512 + lane * 8) = hv;
}

// ---- embedding GEMM (3-pass, exact inputs): x @ emb_w -> emb HI-ONLY frag per t
__global__ __launch_bounds__(256) void gemm_emb(const __bf16* __restrict__ Ah, const __bf16* __restrict__ Al,
    const __bf16* __restrict__ BTh, const __bf16* __restrict__ BTl, __bf16* __restrict__ embf){
  int lane = threadIdx.x & 63, wv = threadIdx.x >> 6;
  int l15 = lane & 15, lg = lane >> 4;
  int col = blockIdx.y * 64 + wv * 16 + l15;
  const __bf16* bh_p = BTh + (size_t)col * VOC + lg * 8;
  const __bf16* bl_p = BTl + (size_t)col * VOC + lg * 8;
  size_t abase = (size_t)(blockIdx.x * 64 + l15) * VOC + lg * 8;
  const __bf16* ah_p = Ah + abase;
  const __bf16* al_p = Al + abase;
  f32x4 acc[4];
  #pragma unroll
  for (int m = 0; m < 4; m++){ acc[m][0]=0.f; acc[m][1]=0.f; acc[m][2]=0.f; acc[m][3]=0.f; }
  for (int kc = 0; kc < 16; ++kc){
    bf16x8 bh = *(const bf16x8*)(bh_p + kc * 32);
    bf16x8 bl = *(const bf16x8*)(bl_p + kc * 32);
    bf16x8 ah[4], al[4];
    #pragma unroll
    for (int m = 0; m < 4; m++){
      ah[m] = *(const bf16x8*)(ah_p + (size_t)(m * 16) * VOC + kc * 32);
      al[m] = *(const bf16x8*)(al_p + (size_t)(m * 16) * VOC + kc * 32);
    }
    #pragma unroll
    for (int m = 0; m < 4; m++) acc[m] = __builtin_amdgcn_mfma_f32_16x16x32_bf16(ah[m], bh, acc[m], 0, 0, 0);
    #pragma unroll
    for (int m = 0; m < 4; m++) acc[m] = __builtin_amdgcn_mfma_f32_16x16x32_bf16(al[m], bh, acc[m], 0, 0, 0);
    #pragma unroll
    for (int m = 0; m < 4; m++) acc[m] = __builtin_amdgcn_mfma_f32_16x16x32_bf16(ah[m], bl, acc[m], 0, 0, 0);
  }
  // hi-only frag epilogue: t = blockIdx.x, k-dim = col
  __bf16* bt = embf + (size_t)blockIdx.x * EFSZH;
  int kc = col >> 5, lgA = (col >> 3) & 3, jA = col & 7;
  #pragma unroll
  for (int m = 0; m < 4; m++){
    #pragma unroll
    for (int v = 0; v < 4; v++){
      int l15A = lg * 4 + v;
      size_t oi = (size_t)(kc * 4 + m) * 512 + (size_t)(lgA * 16 + l15A) * 8 + jA;
      bt[oi] = (__bf16)acc[m][v];
    }
  }
}

// ---- output GEMM (3-pass, exact): rn hi/lo frag history @ out_w + bias -> logits f32
__global__ __launch_bounds__(256) void gemm_out(const __bf16* __restrict__ rnf,
    const __bf16* __restrict__ BTh, const __bf16* __restrict__ BTl,
    const float* __restrict__ bias, float* __restrict__ out){
  int lane = threadIdx.x & 63, wv = threadIdx.x >> 6;
  int l15 = lane & 15, lg = lane >> 4;
  int t = blockIdx.x;
  const __bf16* ab = rnf + (size_t)(t + 1) * FRSZ;
  int col = blockIdx.y * 64 + wv * 16 + l15;
  const __bf16* bh_p = BTh + (size_t)col * NNH + lg * 8;
  const __bf16* bl_p = BTl + (size_t)col * NNH + lg * 8;
  int lane8 = lane * 8;
  f32x4 acc[4];
  #pragma unroll
  for (int m = 0; m < 4; m++){ acc[m][0]=0.f; acc[m][1]=0.f; acc[m][2]=0.f; acc[m][3]=0.f; }
  for (int kc = 0; kc < 48; ++kc){
    bf16x8 bh = *(const bf16x8*)(bh_p + kc * 32);
    bf16x8 bl = *(const bf16x8*)(bl_p + kc * 32);
    bf16x8 ah[4], al[4];
    #pragma unroll
    for (int m = 0; m < 4; m++){
      const __bf16* ap = ab + (size_t)(kc * 4 + m) * 1024 + lane8;
      ah[m] = *(const bf16x8*)ap;
      al[m] = *(const bf16x8*)(ap + 512);
    }
    #pragma unroll
    for (int m = 0; m < 4; m++) acc[m] = __builtin_amdgcn_mfma_f32_16x16x32_bf16(ah[m], bh, acc[m], 0, 0, 0);
    #pragma unroll
    for (int m = 0; m < 4; m++) acc[m] = __builtin_amdgcn_mfma_f32_16x16x32_bf16(al[m], bh, acc[m], 0, 0, 0);
    #pragma unroll
    for (int m = 0; m < 4; m++) acc[m] = __builtin_amdgcn_mfma_f32_16x16x32_bf16(ah[m], bl, acc[m], 0, 0, 0);
  }
  #pragma unroll
  for (int m = 0; m < 4; m++){
    int row = t * 64 + m * 16 + lg * 4;
    #pragma unroll
    for (int v = 0; v < 4; v++)
      out[(size_t)(row + v) * VOC + col] = acc[m][v] + bias[col];
  }
}

// ==== single-pass gate-bundled K-split region: A hi, B hi ====
// per kc: 4 A-frags + 4 B-frags, 16 MFMAs. A-ring depth 3, B-ring depth 4 (period 12).
#define AKG(S, KC) { _Pragma("unroll") \
    for (int m = 0; m < 4; m++) \
      Ah##S[m] = *(const bf16x8*)(ap + (size_t)(KC) * 2048 + m * 512 + lane8); }
#define BKG(S, KC) { _Pragma("unroll") \
    for (int g = 0; g < 4; g++) \
      Bh##S[g] = *(const bf16x8*)(bp + (size_t)(KC) * 2048 + g * 512 + lane8); }
#define MM2(SA, SB) { \
    _Pragma("unroll") for (int m = 0; m < 4; m++) _Pragma("unroll") for (int g = 0; g < 4; g++) \
      acc[m * 4 + g] = __builtin_amdgcn_mfma_f32_16x16x32_bf16(Ah##SA[m], Bh##SB[g], acc[m * 4 + g], 0, 0, 0); }

// body i: consume A-set i%3 / B-set i%4, then reload them for kc i+3 / i+4
#define BODY(I, SA, SB) \
  if ((I) < nkc){ \
    MM2(SA, SB) \
    if ((I) + 3 < nkc) AKG(SA, (I) + 3) \
    if ((I) + 4 < nkc) BKG(SB, (I) + 4) \
  }

// nkc in {6,7,8,12}; fully unrolled 12 slots, wave-uniform guards
__device__ __forceinline__ void regionKG(f32x4 (&acc)[16], const __bf16* __restrict__ ap,
                                         const __bf16* __restrict__ bp, int nkc, int lane8)
{
  bf16x8 Ah0[4], Ah1[4], Ah2[4];
  bf16x8 Bh0[4], Bh1[4], Bh2[4], Bh3[4];
  AKG(0, 0) AKG(1, 1) AKG(2, 2)
  BKG(0, 0) BKG(1, 1) BKG(2, 2) BKG(3, 3)
  BODY(0, 0, 0)
  BODY(1, 1, 1)
  BODY(2, 2, 2)
  BODY(3, 0, 3)
  BODY(4, 1, 0)
  BODY(5, 2, 1)
  BODY(6, 0, 2)
  BODY(7, 1, 3)
  BODY(8, 2, 0)
  BODY(9, 0, 1)
  BODY(10, 1, 2)
  BODY(11, 2, 3)
}

// ---- fused pipelined LSTM step: blocks 0..95 = layer0 step k; 96..191 = layer1 step k-1
// 8 waves: each wave computes full 64-col tile (16 n x 4 gates) over 1/8 of K.
// Two-stage pairwise K-reduction; h0/h1 hot hi-only ping-pong;
// rnf history keeps hi/lo (NT-streamed) so the final projection stays exact.
__global__ __launch_bounds__(512, 2) void lstm_step(int k,
  const __bf16* __restrict__ w0f, const __bf16* __restrict__ w1f,
  const float* __restrict__ b0, const float* __restrict__ b1,
  const __bf16* __restrict__ embt,
  const __bf16* __restrict__ h0r, __bf16* __restrict__ h0w,
  const __bf16* __restrict__ h1r, __bf16* __restrict__ h1w,
  __bf16* __restrict__ rnh,
  float* __restrict__ c0, float* __restrict__ c1)
{
  const bool isB = blockIdx.x >= 96;
  if (!isB && k == TT) return;
  if (isB && k == 0) return;
  const int blk = isB ? (blockIdx.x - 96) : blockIdx.x;
  const int n0 = blk * 16;
  const int lane = threadIdx.x & 63, wv = threadIdx.x >> 6;
  const int l15 = lane & 15, lg = lane >> 4;
  const int lane8 = lane * 8;

  f32x4 acc[16];
  #pragma unroll
  for (int i = 0; i < 16; i++){ acc[i][0]=0.f; acc[i][1]=0.f; acc[i][2]=0.f; acc[i][3]=0.f; }

  if (isB){
    // 96 kc; wave wv: kc [wv*12, wv*12+12); waves 0-3 read h0(t), 4-7 read h1(t-2)
    const __bf16* ap = (wv < 4) ? (h0r + (size_t)(wv * 12) * 2048)
                                : (h1r + (size_t)((wv - 4) * 12) * 2048);
    const __bf16* bp = w1f + ((size_t)blk * 96 + wv * 12) * 2048;
    regionKG(acc, ap, bp, 12, lane8);
  } else {
    // 56 kc = [emb 8 | h0 48]; quotas: wv0=8(emb), wv1-6=7, wv7=6
    int gstart = (wv == 0) ? 0 : (8 + (wv - 1) * 7);
    int nkc = (wv == 0) ? 8 : ((wv == 7) ? 6 : 7);
    const __bf16* ap = (wv == 0) ? embt : (h0r + (size_t)(gstart - 8) * 2048);
    const __bf16* bp = w0f + ((size_t)blk * 56 + gstart) * 2048;
    regionKG(acc, ap, bp, nkc, lane8);
  }

  // two-stage K-partial reduction: 8 partials -> 4 in LDS -> epilogue sums 4
  __shared__ float lin[4][64][68];   // [wavepair][col(g*16+l15)][row(batch), pad 68], ~68 KB
  if (wv >= 4){
    #pragma unroll
    for (int m = 0; m < 4; m++)
      #pragma unroll
      for (int g = 0; g < 4; g++)
        *(f32x4*)&lin[wv - 4][g * 16 + l15][m * 16 + lg * 4] = acc[m * 4 + g];
  }
  __syncthreads();
  if (wv < 4){
    #pragma unroll
    for (int m = 0; m < 4; m++)
      #pragma unroll
      for (int g = 0; g < 4; g++){
        f32x4 part = *(const f32x4*)&lin[wv][g * 16 + l15][m * 16 + lg * 4];
        acc[m * 4 + g][0] += part[0]; acc[m * 4 + g][1] += part[1];
        acc[m * 4 + g][2] += part[2]; acc[m * 4 + g][3] += part[3];
        *(f32x4*)&lin[wv][g * 16 + l15][m * 16 + lg * 4] = acc[m * 4 + g];
      }
  }
  __syncthreads();

  const float* bias = isB ? b1 : b0;
  float* cst = isB ? c1 : c0;
  __bf16* of = isB ? h1w : h0w;
  const int j = threadIdx.x & 15, rr = threadIdx.x >> 4;   // j: n_rel, rr: 0..31
  #pragma unroll
  for (int half = 0; half < 2; half++){
    int r = rr + half * 32;   // batch row
    float s0 = 0.f, s1 = 0.f, s2 = 0.f, s3 = 0.f;
    #pragma unroll
    for (int w = 0; w < 4; w++){
      s0 += lin[w][j][r];
      s1 += lin[w][16 + j][r];
      s2 += lin[w][32 + j][r];
      s3 += lin[w][48 + j][r];
    }
    int n = n0 + j;
    float fv = sigm_(s0 + bias[n]);
    float iv = sigm_(s1 + bias[NNH + n]);
    float ov = sigm_(s2 + bias[2 * NNH + n]);
    float gv = tanh_(s3 + bias[3 * NNH + n]);
    int ci = r * NNH + n;
    float cn = fv * cst[ci] + iv * gv;
    cst[ci] = cn;
    float hn = ov * tanh_(cn);
    __bf16 hb = (__bf16)hn;
    int kcp = n >> 5, lgA = (n >> 3) & 3, j8 = n & 7, mb = r >> 4, l15b = r & 15;
    // hot hi-only recurrent state
    size_t oh = (size_t)(kcp * 4 + mb) * 512 + (size_t)(lgA * 16 + l15b) * 8 + j8;
    of[oh] = hb;
    if (isB){
      // cold hi/lo history copy for exact gemm_out: stream to HBM
      __bf16 lb = (__bf16)(hn - (float)hb);
      size_t oi = (size_t)(kcp * 4 + mb) * 1024 + (size_t)(lgA * 16 + l15b) * 8 + j8;
      __builtin_nontemporal_store(hb, &rnh[oi]);
      __builtin_nontemporal_store(lb, &rnh[oi + 512]);
    }
  }
}

extern "C" void kernel_launch(void* const* d_in, const int* in_sizes, int n_in,
                              void* d_out, int out_size, void* d_ws, size_t ws_size,
                              hipStream_t stream)
{
  (void)in_sizes; (void)n_in; (void)out_size;
  const float* x_in = (const float*)d_in[0];
  const float* emw  = (const float*)d_in[1];
  const float* w0   = (const float*)d_in[2];
  const float* b0   = (const float*)d_in[3];
  const float* w1   = (const float*)d_in[4];
  const float* b1   = (const float*)d_in[5];
  const float* outw = (const float*)d_in[6];
  const float* outb = (const float*)d_in[7];
  const float* h0i  = (const float*)d_in[8];
  const float* c0i  = (const float*)d_in[9];
  const float* h1i  = (const float*)d_in[10];
  const float* c1i  = (const float*)d_in[11];
  float* logits = (float*)d_out;

  char* p = (char*)d_ws;
  auto ab = [&](size_t bytes)->char*{ char* r = p; p += (bytes + 255) & ~(size_t)255; return r; };
  __bf16* w0f  = (__bf16*)ab((size_t)96 * 56 * 4 * 1024);   // 22.0 MB hi-only stream
  __bf16* w1f  = (__bf16*)ab((size_t)96 * 96 * 4 * 1024);   // 37.7 MB
  __bf16* ewTh = (__bf16*)ab((size_t)EMBD * VOC * 2);
  __bf16* ewTl = (__bf16*)ab((size_t)EMBD * VOC * 2);
  __bf16* owTh = (__bf16*)ab((size_t)VOC * NNH * 2);
  __bf16* owTl = (__bf16*)ab((size_t)VOC * NNH * 2);
  __bf16* xh   = (__bf16*)ab((size_t)TT * BB * VOC * 2);
  __bf16* xl   = (__bf16*)ab((size_t)TT * BB * VOC * 2);
  __bf16* embf = (__bf16*)ab((size_t)TT * EFSZH * 2);       // 8.4 MB hi-only frag
  __bf16* rnf  = (__bf16*)ab((size_t)(TT + 1) * FRSZ * 2);  // 101 MB hi/lo history (NT)
  __bf16* h0f  = (__bf16*)ab((size_t)2 * FRSZH * 2);        // h0 hi-only ping-pong (hot)
  __bf16* h1f  = (__bf16*)ab((size_t)2 * FRSZH * 2);        // h1 hi-only ping-pong (hot)
  float* c0 = (float*)ab((size_t)BB * NNH * 4);
  float* c1 = (float*)ab((size_t)BB * NNH * 4);
  if ((size_t)(p - (char*)d_ws) > ws_size) return;  // ws too small: fail visibly

  const int H = BB * NNH;

  // one-time-per-call prep
  wfrag<<<96 * 56 * 4 / 4, 256, 0, stream>>>(w0, 56, w0f);
  wfrag<<<96 * 96 * 4 / 4, 256, 0, stream>>>(w1, 96, w1f);
  tsplit<<<dim3(EMBD / 32, VOC / 32), 256, 0, stream>>>(emw, VOC, EMBD, ewTh, ewTl);
  tsplit<<<dim3(VOC / 32, NNH / 32), 256, 0, stream>>>(outw, NNH, VOC, owTh, owTl);
  {
    int nin = TT * BB * VOC;
    vsplit<<<nin / 256, 256, 0, stream>>>(x_in, nin, xh, xl);
  }
  vsplit_fragH<<<H / 256, 256, 0, stream>>>(h0i, h0f + FRSZH);  // h0 parity 1 (read at k=0)
  vsplit_fragH<<<H / 256, 256, 0, stream>>>(h1i, h1f);          // h1 parity 0 (read at k=1)
  hipMemcpyAsync(c0, c0i, (size_t)H * 4, hipMemcpyDeviceToDevice, stream);
  hipMemcpyAsync(c1, c1i, (size_t)H * 4, hipMemcpyDeviceToDevice, stream);

  // embedding -> hi-only frag emb buffer
  gemm_emb<<<dim3(TT * BB / 64, EMBD / 64), 256, 0, stream>>>(xh, xl, ewTh, ewTl, embf);

  // pipelined recurrence: kernel k = layer0 step k + layer1 step k-1
  for (int k = 0; k <= TT; ++k){
    int tA = (k < TT) ? k : 0;
    lstm_step<<<192, 512, 0, stream>>>(k, w0f, w1f, b0, b1,
        embf + (size_t)tA * EFSZH,
        h0f + (size_t)((k + 1) & 1) * FRSZH, h0f + (size_t)(k & 1) * FRSZH,
        h1f + (size_t)((k + 1) & 1) * FRSZH, h1f + (size_t)(k & 1) * FRSZH,
        rnf + (size_t)k * FRSZ,
        c0, c1);
  }

  // logits = rn hi/lo frag history @ out_w + out_b (exact 3-pass)
  gemm_out<<<dim3(TT, VOC / 64), 256, 0, stream>>>(rnf, owTh, owTl, outb, logits);
}